// Round 7
// baseline (222.099 us; speedup 1.0000x reference)
//
#include <hip/hip_runtime.h>

// PointPillarScatter3d on MI355X (gfx950)
// NZ=1, NY=NX=512, C=128, B=4, P=320000.
// Strategy: scatter->gather inversion + channel-sliced gather for long write runs.
//   hipMemsetAsync: map[B*CELLS] = -1
//   k_scatter_idx:  map[b*CELLS + cell] = point index (cells unique per batch)
//   k_gather:       block = 32 channels x 512 cells (cg = channel group 0..3).
//     Phase B: per occupied cell, one 128B feat slice (8 lanes x float4,
//              128B-aligned -> 2 full 64B granules, no amplification).
//     Phase C: per channel, 2KB contiguous output run (2 waves x 1KB float4 stores)
//              -> 4x longer DRAM write runs than R6 (512B).
//   cg in low blockIdx bits: the 4 slice-readers of a feat row run ~concurrently.
//   Full output covered -> zeros from LDS for empty cells, no separate zero pass.

#define NXD 512
#define NYD 512
#define NZD 1
#define CB  128
#define CELLS (NXD * NYD * NZD)   // 262144

#define SPAN 512                  // cells per block
#define CGS  4                    // channel groups of 32
#define CGW  32                   // channels per group
#define NTHR 512

typedef float f4 __attribute__((ext_vector_type(4)));

__global__ void k_scatter_idx(const int* __restrict__ coords,
                              int* __restrict__ map, int P) {
    int p = blockIdx.x * blockDim.x + threadIdx.x;
    if (p >= P) return;
    int4 c = ((const int4*)coords)[p];      // (b, z, y, x)
    int cell = c.y * (NYD * NXD) + c.z * NXD + c.w;
    map[c.x * CELLS + cell] = p;
}

__global__ __launch_bounds__(NTHR) void k_gather(const float* __restrict__ feat,
                                                 const int* __restrict__ map,
                                                 float* __restrict__ out) {
    __shared__ int   pidx[SPAN];
    __shared__ float ldsT[CGW][SPAN];       // 64 KB

    const int t    = threadIdx.x;
    const int cg   = blockIdx.x & (CGS - 1);
    const int rest = blockIdx.x >> 2;
    const int span = rest & (CELLS / SPAN - 1);   // 0..511
    const int b    = rest >> 9;
    const int cell_base = span * SPAN;

    pidx[t] = map[b * CELLS + cell_base + t];
    __syncthreads();

    // Phase B: 8 lanes x float4 = one 128B row-slice; 64 cells per pass, 8 passes.
    {
        const int q  = t & 7;      // float4 column within the 32-ch slice
        const int xc = t >> 3;     // 0..63 cell within pass
        int idxr[8];
        #pragma unroll
        for (int p = 0; p < 8; ++p) idxr[p] = pidx[p * 64 + xc];
        #pragma unroll
        for (int p = 0; p < 8; ++p) {
            const int x = p * 64 + xc;
            f4 v = (f4)(0.f);
            if (idxr[p] >= 0)
                v = ((const f4*)feat)[(size_t)idxr[p] * (CB / 4) + cg * 8 + q];
            ldsT[q * 4 + 0][x] = v.x;
            ldsT[q * 4 + 1][x] = v.y;
            ldsT[q * 4 + 2][x] = v.z;
            ldsT[q * 4 + 3][x] = v.w;
        }
    }
    __syncthreads();

    // Phase C: 4 channels x 128 float4-slots per pass, 8 passes.
    // Per wave instruction: 64 lanes x 16B = 1KB contiguous; 2KB per channel per block.
    {
        const int x4 = t & 127;    // float4 index along 512 cells
        const int c0 = t >> 7;     // 0..3
        float* outb = out + (size_t)b * CB * CELLS + cell_base;
        #pragma unroll
        for (int p = 0; p < 8; ++p) {
            const int c = p * 4 + c0;                 // local channel 0..31
            f4 v = *(const f4*)&ldsT[c][x4 * 4];
            *(f4*)(outb + (size_t)(cg * CGW + c) * CELLS + x4 * 4) = v;
        }
    }
}

extern "C" void kernel_launch(void* const* d_in, const int* in_sizes, int n_in,
                              void* d_out, int out_size, void* d_ws, size_t ws_size,
                              hipStream_t stream) {
    const float* feat   = (const float*)d_in[1];
    const int*   coords = (const int*)d_in[2];
    float*       out    = (float*)d_out;
    int*         map    = (int*)d_ws;   // B*CELLS int32 = 4 MB

    const int B = out_size / (CB * CELLS);
    const int P = in_sizes[1] / CB;
    const int n_map = B * CELLS;

    (void)hipMemsetAsync(map, 0xFF, (size_t)n_map * sizeof(int), stream);
    k_scatter_idx<<<(P + 255) / 256, 256, 0, stream>>>(coords, map, P);
    k_gather<<<B * (CELLS / SPAN) * CGS, NTHR, 0, stream>>>(feat, map, out);
}